// Round 1
// 1052.384 us; speedup vs baseline: 1.1893x; 1.1893x over previous
//
#include <hip/hip_runtime.h>
#include <hip/hip_bf16.h>

// ---------------------------------------------------------------------------
// MoELayer, fp32 inputs/outputs (reference dtype). Pre-router path computed
// via split-bf16 (hi+lo) 3-term MFMA for fp32 fidelity (routing argmax must
// match numpy). Post-routing expert GEMMs: bf16 A x fp32 W (converted at
// stage) -> bf16 MFMA; weights fetched exactly once (HBM floor).
// ---------------------------------------------------------------------------

typedef unsigned int u32;
typedef unsigned short u16;
typedef __attribute__((ext_vector_type(8))) u16 u16x8;
typedef __attribute__((ext_vector_type(4))) float f32x4;
typedef __attribute__((ext_vector_type(8))) __bf16 bf16x8;

#define N_TOK 2048
#define DMODEL 1024
#define FEXP 4096
#define NEXP 16
#define CAP 160

__device__ __forceinline__ float b2f(u16 u) {
  u32 x = ((u32)u) << 16;
  return __builtin_bit_cast(float, x);
}
__device__ __forceinline__ u16 f2b(float f) {  // RNE
  u32 i = __builtin_bit_cast(u32, f);
  u32 r = (i + 0x7fffu + ((i >> 16) & 1u)) >> 16;
  return (u16)r;
}

__device__ __forceinline__ f32x4 mfma16(u16x8 a, u16x8 b, f32x4 c) {
  return __builtin_amdgcn_mfma_f32_16x16x32_bf16(
      __builtin_bit_cast(bf16x8, a), __builtin_bit_cast(bf16x8, b), c, 0, 0, 0);
}

// async global->LDS, 16B/lane; LDS dest = wave-uniform base + lane*16
__device__ __forceinline__ void gll16(const void* g, void* lds) {
  __builtin_amdgcn_global_load_lds(
      (const __attribute__((address_space(1))) u32*)(unsigned long long)(uintptr_t)g,
      (__attribute__((address_space(3))) u32*)(u32)(uintptr_t)lds, 16, 0, 0);
}

// ---------------------------------------------------------------------------
// fp32 -> bf16 hi/lo split (weights pre-pass)
// ---------------------------------------------------------------------------
__global__ __launch_bounds__(256) void split_kernel(const float *s, u16 *hi, u16 *lo, int n4) {
  const int i = blockIdx.x * 256 + threadIdx.x;
  if (i >= n4) return;
  const float4 v = ((const float4 *)s)[i];
  const u16 h0 = f2b(v.x), h1 = f2b(v.y), h2 = f2b(v.z), h3 = f2b(v.w);
  const u16 l0 = f2b(v.x - b2f(h0)), l1 = f2b(v.y - b2f(h1));
  const u16 l2 = f2b(v.z - b2f(h2)), l3 = f2b(v.w - b2f(h3));
  ((uint2 *)hi)[i] = make_uint2((u32)h0 | ((u32)h1 << 16), (u32)h2 | ((u32)h3 << 16));
  ((uint2 *)lo)[i] = make_uint2((u32)l0 | ((u32)l1 << 16), (u32)l2 | ((u32)l3 << 16));
}

// ---------------------------------------------------------------------------
// Dense split GEMM: C[M,Nc] = A @ W^T + bias; A,W given as bf16 hi/lo pairs.
// 3-term product: aH*wH + aL*wH + aH*wL  (error ~2^-18 rel).
// Tile 128x128, 4 waves 2x2. Output: split pair (Ch,Cl) or fp32 Cf (+Rres).
// ---------------------------------------------------------------------------
struct GemmSP {
  const u16 *Ah, *Al; long sA; int lda;
  const u16 *Wh, *Wl; long sWp;
  const float *bias; long sB;      // sB<0 -> select B0..B2 by z
  const float *B0, *B1, *B2;
  const float *Rres;               // optional fp32 residual (z==0)
  u16 *Ch, *Cl; float *Cf;
  long sC; int ldc; int K;
};

__global__ __launch_bounds__(256) void gemm_split(GemmSP p) {
  __shared__ u16 AsH[4096], AsL[4096], BsH[4096], BsL[4096];
  const int tid = threadIdx.x, lane = tid & 63, wave = tid >> 6;
  const int z = blockIdx.z;
  const int m0 = blockIdx.x * 128, n0 = blockIdx.y * 128;
  const u16 *Ah = p.Ah + (long)z * p.sA;
  const u16 *Al = p.Al + (long)z * p.sA;
  const u16 *Wh = p.Wh + (long)z * p.sWp;
  const u16 *Wl = p.Wl + (long)z * p.sWp;
  const float *bias = (p.sB >= 0) ? (p.bias + (long)z * p.sB)
                                  : (z == 0 ? p.B0 : z == 1 ? p.B1 : p.B2);
  const int K = p.K;
  const int srow = tid >> 2, scol = (tid & 3) * 8;
  const int R0 = (wave >> 1) * 64, C0 = (wave & 1) * 64;
  const int l15 = lane & 15, quad = lane >> 4;

  f32x4 acc[4][4];
#pragma unroll
  for (int i = 0; i < 4; ++i)
#pragma unroll
    for (int j = 0; j < 4; ++j) acc[i][j] = (f32x4){0.f, 0.f, 0.f, 0.f};

  for (int s = 0; s < (K >> 5); ++s) {
    const int kk = s << 5;
    __syncthreads();
#pragma unroll
    for (int h = 0; h < 2; ++h) {
      const long ao = (long)(m0 + h * 64 + srow) * p.lda + kk + scol;
      gll16(Ah + ao, &AsH[(h * 64 + wave * 16) * 32]);
      gll16(Al + ao, &AsL[(h * 64 + wave * 16) * 32]);
      const long bo = (long)(n0 + h * 64 + srow) * K + kk + scol;
      gll16(Wh + bo, &BsH[(h * 64 + wave * 16) * 32]);
      gll16(Wl + bo, &BsL[(h * 64 + wave * 16) * 32]);
    }
    __syncthreads();  // drains vmcnt -> staged data visible
    u16x8 aH[4], aL[4], bH[4], bL[4];
#pragma unroll
    for (int i = 0; i < 4; ++i) {
      aH[i] = *(const u16x8 *)&AsH[(R0 + i * 16 + l15) * 32 + quad * 8];
      aL[i] = *(const u16x8 *)&AsL[(R0 + i * 16 + l15) * 32 + quad * 8];
    }
#pragma unroll
    for (int j = 0; j < 4; ++j) {
      bH[j] = *(const u16x8 *)&BsH[(C0 + j * 16 + l15) * 32 + quad * 8];
      bL[j] = *(const u16x8 *)&BsL[(C0 + j * 16 + l15) * 32 + quad * 8];
    }
#pragma unroll
    for (int i = 0; i < 4; ++i)
#pragma unroll
      for (int j = 0; j < 4; ++j) {
        acc[i][j] = mfma16(aH[i], bH[j], acc[i][j]);
        acc[i][j] = mfma16(aL[i], bH[j], acc[i][j]);
        acc[i][j] = mfma16(aH[i], bL[j], acc[i][j]);
      }
  }

  // epilogue: C/D layout col=lane&15, row=quad*4+reg
#pragma unroll
  for (int j = 0; j < 4; ++j) {
    const int n = n0 + C0 + j * 16 + l15;
    const float bv = bias[n];
#pragma unroll
    for (int i = 0; i < 4; ++i)
#pragma unroll
      for (int r = 0; r < 4; ++r) {
        const int m = m0 + R0 + i * 16 + quad * 4 + r;
        float v = acc[i][j][r] + bv;
        if (p.Rres) v += p.Rres[(long)m * p.ldc + n];
        const long idx = (long)m * p.ldc + n + (long)z * p.sC;
        if (p.Cf) p.Cf[idx] = v;
        else {
          const u16 hh = f2b(v);
          p.Ch[idx] = hh;
          p.Cl[idx] = f2b(v - b2f(hh));
        }
      }
  }
}

// ---------------------------------------------------------------------------
// LayerNorm
// ---------------------------------------------------------------------------
__device__ __forceinline__ float block_sum(float v, float *red) {
#pragma unroll
  for (int off = 32; off > 0; off >>= 1) v += __shfl_xor(v, off);
  const int w = threadIdx.x >> 6;
  __syncthreads();
  if ((threadIdx.x & 63) == 0) red[w] = v;
  __syncthreads();
  return red[0] + red[1] + red[2] + red[3];
}

__global__ __launch_bounds__(256) void ln1_kernel(const float *x, const float *w,
                                                  const float *b, u16 *Hh, u16 *Hl) {
  __shared__ float red[4];
  const int n = blockIdx.x, t = threadIdx.x;
  const float4 u = ((const float4 *)(x + (long)n * DMODEL))[t];
  float v[4] = {u.x, u.y, u.z, u.w};
  const float mean = block_sum(v[0] + v[1] + v[2] + v[3], red) * (1.f / DMODEL);
  float s2 = 0.f;
#pragma unroll
  for (int i = 0; i < 4; ++i) { float d = v[i] - mean; s2 += d * d; }
  const float var = block_sum(s2, red) * (1.f / DMODEL);
  const float rstd = 1.f / sqrtf(var + 1e-5f);
#pragma unroll
  for (int i = 0; i < 4; ++i) {
    const int c = t * 4 + i;
    const float y = (v[i] - mean) * rstd * w[c] + b[c];
    const u16 hh = f2b(y);
    Hh[(long)n * DMODEL + c] = hh;
    Hl[(long)n * DMODEL + c] = f2b(y - b2f(hh));
  }
}

__global__ __launch_bounds__(256) void ln2_kernel(const float *xin, const float *w,
                                                  const float *b, float *h2f, u16 *h2b) {
  __shared__ float red[4];
  const int n = blockIdx.x, t = threadIdx.x;
  const float4 u = ((const float4 *)(xin + (long)n * DMODEL))[t];
  float v[4] = {u.x, u.y, u.z, u.w};
  const float mean = block_sum(v[0] + v[1] + v[2] + v[3], red) * (1.f / DMODEL);
  float s2 = 0.f;
#pragma unroll
  for (int i = 0; i < 4; ++i) { float d = v[i] - mean; s2 += d * d; }
  const float var = block_sum(s2, red) * (1.f / DMODEL);
  const float rstd = 1.f / sqrtf(var + 1e-5f);
#pragma unroll
  for (int i = 0; i < 4; ++i) {
    const int c = t * 4 + i;
    const float y = (v[i] - mean) * rstd * w[c] + b[c];
    h2f[(long)n * DMODEL + c] = y;
    h2b[(long)n * DMODEL + c] = f2b(y);
  }
}

// ---------------------------------------------------------------------------
// V transpose: QKV[:,2048:3072] (hi/lo) -> Vt [1024][2048] so attention can
// stage V^T with vector loads (kills the per-element LDS transpose).
// ---------------------------------------------------------------------------
__global__ __launch_bounds__(256) void vtrans_kernel(const u16 *QKVh, const u16 *QKVl,
                                                     u16 *Vtgh, u16 *Vtgl) {
  __shared__ u16 Th[64][72], Tl[64][72];
  const int n0 = blockIdx.x * 64, c0 = blockIdx.y * 64;
  const int t = threadIdx.x;
  const int r = t >> 2, cc = (t & 3) * 16;
  {
    const long src = (long)(n0 + r) * 3072 + 2048 + c0 + cc;
    *(u16x8 *)&Th[r][cc] = *(const u16x8 *)(QKVh + src);
    *(u16x8 *)&Th[r][cc + 8] = *(const u16x8 *)(QKVh + src + 8);
    *(u16x8 *)&Tl[r][cc] = *(const u16x8 *)(QKVl + src);
    *(u16x8 *)&Tl[r][cc + 8] = *(const u16x8 *)(QKVl + src + 8);
  }
  __syncthreads();
  u16x8 oh[2], ol[2];
#pragma unroll
  for (int j = 0; j < 2; ++j)
#pragma unroll
    for (int k = 0; k < 8; ++k) {
      oh[j][k] = Th[cc + j * 8 + k][r];
      ol[j][k] = Tl[cc + j * 8 + k][r];
    }
  const long dst = (long)(c0 + r) * 2048 + n0 + cc;
  *(u16x8 *)(Vtgh + dst) = oh[0];
  *(u16x8 *)(Vtgh + dst + 8) = oh[1];
  *(u16x8 *)(Vtgl + dst) = ol[0];
  *(u16x8 *)(Vtgl + dst + 8) = ol[1];
}

// ---------------------------------------------------------------------------
// Flash attention: block = (64 q-rows, 1 head), 4 waves x 16 q-rows.
// QKV: [2048,3072] bf16 hi/lo pairs (q|k|v); V additionally pre-transposed in
// global (Vtg). Double-buffered padded LDS tiles (all vector ds ops, <=2-way
// banks), one barrier per k-tile, issue-early/write-late staging.
// QK^T 3-term, PV 3-term, exp2-domain softmax.
// Grid: 1-D 512 with cost-complementary swizzle: any HW pairing (id,id+256)
// or (2c,2c+1) gives qb+qb'=31 -> every CU carries ~66 block-steps.
// ---------------------------------------------------------------------------
__global__ __launch_bounds__(256) void attn_kernel(const u16 *QKVh, const u16 *QKVl,
                                                   const u16 *Vtgh, const u16 *Vtgl,
                                                   u16 *CTh, u16 *CTl) {
  __shared__ u16 Ksh[2][32][72], Ksl[2][32][72];   // stride 144B: 16B-aligned, 2-way banks
  __shared__ u16 Vsh[2][64][40], Vsl[2][64][40];   // stride 80B
  __shared__ u16 Psh[4][16][40], Psl[4][16][40];   // per-wave P transpose buffer
  const int tid = threadIdx.x, lane = tid & 63, wave = tid >> 6;
  const int id = blockIdx.x;
  const int uu = id & 255, hi = id >> 8, pp = uu & 1, up = uu >> 1;
  const int g = up >> 2;
  const int qb = (pp ^ hi) ? (31 - g) : g;
  const int head = ((up & 3) << 2) | (pp << 1) | hi;
  const int q0 = qb * 64;
  const int l15 = lane & 15, quad = lane >> 4;
  const int qrow = q0 + wave * 16;

  u16x8 aQh[2], aQl[2];
  {
    const long base = (long)(qrow + l15) * 3072 + head * 64 + quad * 8;
    aQh[0] = *(const u16x8 *)(QKVh + base);
    aQh[1] = *(const u16x8 *)(QKVh + base + 32);
    aQl[0] = *(const u16x8 *)(QKVl + base);
    aQl[1] = *(const u16x8 *)(QKVl + base + 32);
  }
  f32x4 o[4];
#pragma unroll
  for (int j = 0; j < 4; ++j) o[j] = (f32x4){0.f, 0.f, 0.f, 0.f};
  f32x4 m_run = {-1e30f, -1e30f, -1e30f, -1e30f};
  f32x4 l_run = {0.f, 0.f, 0.f, 0.f};

  const int ktiles = (q0 + 64) >> 5;
  // staging decomposition: K tile 32 rows x 64 d (8x16B chunks/row),
  //                        V^T tile 64 rows x 32 tok (4x16B chunks/row)
  const int kr = tid >> 3, kc = (tid & 7) * 8;
  const int vr = tid >> 2, vc = (tid & 3) * 8;
  const long kgbase = 1024 + head * 64 + kc;
  const long vgbase = (long)(head * 64 + vr) * 2048 + vc;

  u16x8 skh, skl, svh, svl;
  {  // prologue: stage tile 0 into buffer 0
    const long ks = (long)kr * 3072 + kgbase;
    skh = *(const u16x8 *)(QKVh + ks);
    skl = *(const u16x8 *)(QKVl + ks);
    svh = *(const u16x8 *)(Vtgh + vgbase);
    svl = *(const u16x8 *)(Vtgl + vgbase);
    *(u16x8 *)&Ksh[0][kr][kc] = skh;
    *(u16x8 *)&Ksl[0][kr][kc] = skl;
    *(u16x8 *)&Vsh[0][vr][vc] = svh;
    *(u16x8 *)&Vsl[0][vr][vc] = svl;
  }
  __syncthreads();

  constexpr float SC = 0.125f * 1.4426950408889634f;  // 1/sqrt(64) * log2(e)

  for (int t = 0; t < ktiles; ++t) {
    const int b = t & 1;
    const int kt0 = t << 5;
    const bool pf = (t + 1 < ktiles);
    if (pf) {  // issue next-tile global loads early (latency hides under compute)
      const long ks = (long)(kt0 + 32 + kr) * 3072 + kgbase;
      skh = *(const u16x8 *)(QKVh + ks);
      skl = *(const u16x8 *)(QKVl + ks);
      svh = *(const u16x8 *)(Vtgh + vgbase + kt0 + 32);
      svl = *(const u16x8 *)(Vtgl + vgbase + kt0 + 32);
    }
    if (kt0 <= qrow + 15) {
      f32x4 s0 = {0.f, 0.f, 0.f, 0.f}, s1 = {0.f, 0.f, 0.f, 0.f};
#pragma unroll
      for (int c = 0; c < 2; ++c) {
        const u16x8 bh0 = *(const u16x8 *)&Ksh[b][l15][c * 32 + quad * 8];
        const u16x8 bl0 = *(const u16x8 *)&Ksl[b][l15][c * 32 + quad * 8];
        const u16x8 bh1 = *(const u16x8 *)&Ksh[b][16 + l15][c * 32 + quad * 8];
        const u16x8 bl1 = *(const u16x8 *)&Ksl[b][16 + l15][c * 32 + quad * 8];
        s0 = mfma16(aQh[c], bh0, s0);
        s0 = mfma16(aQl[c], bh0, s0);
        s0 = mfma16(aQh[c], bl0, s0);
        s1 = mfma16(aQh[c], bh1, s1);
        s1 = mfma16(aQl[c], bh1, s1);
        s1 = mfma16(aQh[c], bl1, s1);
      }
      f32x4 rm;
#pragma unroll
      for (int r = 0; r < 4; ++r) {
        const int qg = qrow + quad * 4 + r;
        s0[r] *= SC; s1[r] *= SC;
        if (kt0 + l15 > qg) s0[r] = -1e30f;
        if (kt0 + 16 + l15 > qg) s1[r] = -1e30f;
        rm[r] = fmaxf(s0[r], s1[r]);
      }
#pragma unroll
      for (int off = 1; off < 16; off <<= 1)
#pragma unroll
        for (int r = 0; r < 4; ++r) rm[r] = fmaxf(rm[r], __shfl_xor(rm[r], off));
      f32x4 al, p0, p1, rs;
#pragma unroll
      for (int r = 0; r < 4; ++r) {
        const float mn = fmaxf(m_run[r], rm[r]);
        al[r] = exp2f(m_run[r] - mn);
        p0[r] = exp2f(s0[r] - mn);
        p1[r] = exp2f(s1[r] - mn);
        m_run[r] = mn;
        rs[r] = p0[r] + p1[r];
      }
#pragma unroll
      for (int off = 1; off < 16; off <<= 1)
#pragma unroll
        for (int r = 0; r < 4; ++r) rs[r] += __shfl_xor(rs[r], off);
#pragma unroll
      for (int r = 0; r < 4; ++r) l_run[r] = l_run[r] * al[r] + rs[r];
#pragma unroll
      for (int j4 = 0; j4 < 4; ++j4)
#pragma unroll
        for (int r = 0; r < 4; ++r) o[j4][r] *= al[r];
#pragma unroll
      for (int r = 0; r < 4; ++r) {
        const int rl = quad * 4 + r;
        const u16 h0 = f2b(p0[r]);
        Psh[wave][rl][l15] = h0;
        Psl[wave][rl][l15] = f2b(p0[r] - b2f(h0));
        const u16 h1 = f2b(p1[r]);
        Psh[wave][rl][16 + l15] = h1;
        Psl[wave][rl][16 + l15] = f2b(p1[r] - b2f(h1));
      }
      const u16x8 aPh = *(const u16x8 *)&Psh[wave][l15][quad * 8];
      const u16x8 aPl = *(const u16x8 *)&Psl[wave][l15][quad * 8];
#pragma unroll
      for (int j4 = 0; j4 < 4; ++j4) {
        const u16x8 bvh = *(const u16x8 *)&Vsh[b][j4 * 16 + l15][quad * 8];
        const u16x8 bvl = *(const u16x8 *)&Vsl[b][j4 * 16 + l15][quad * 8];
        o[j4] = mfma16(aPh, bvh, o[j4]);
        o[j4] = mfma16(aPh, bvl, o[j4]);
        o[j4] = mfma16(aPl, bvh, o[j4]);
      }
    }
    if (pf) {  // write-late into the other buffer
      const int b2 = b ^ 1;
      *(u16x8 *)&Ksh[b2][kr][kc] = skh;
      *(u16x8 *)&Ksl[b2][kr][kc] = skl;
      *(u16x8 *)&Vsh[b2][vr][vc] = svh;
      *(u16x8 *)&Vsl[b2][vr][vc] = svl;
    }
    __syncthreads();
  }
#pragma unroll
  for (int j4 = 0; j4 < 4; ++j4)
#pragma unroll
    for (int r = 0; r < 4; ++r) {
      const float v = o[j4][r] / l_run[r];
      const long row = qrow + quad * 4 + r;
      const long col = head * 64 + j4 * 16 + l15;
      const u16 hh = f2b(v);
      CTh[row * 1024 + col] = hh;
      CTl[row * 1024 + col] = f2b(v - b2f(hh));
    }
}

// ---------------------------------------------------------------------------
// Router (fp32): one wave per token; lane (e=lane>>2, j=lane&3)
// ---------------------------------------------------------------------------
__global__ __launch_bounds__(64) void router_kernel(const float *h2f, const float *rw,
                                                    const float *rb, float *pmax, int *route) {
  const int n = blockIdx.x, lane = threadIdx.x;
  const int e = lane >> 2, j = lane & 3;
  const float4 *wp = (const float4 *)(rw + (long)e * DMODEL + j * 256);
  const float4 *hp = (const float4 *)(h2f + (long)n * DMODEL + j * 256);
  float acc = 0.f;
  for (int i = 0; i < 64; ++i) {
    const float4 w = wp[i], h = hp[i];
    acc += h.x * w.x + h.y * w.y + h.z * w.z + h.w * w.w;
  }
  acc += __shfl_xor(acc, 1);
  acc += __shfl_xor(acc, 2);
  float lv[16];
#pragma unroll
  for (int ee = 0; ee < 16; ++ee) lv[ee] = __shfl(acc, ee * 4) + rb[ee];
  float mx = lv[0]; int am = 0;
#pragma unroll
  for (int ee = 1; ee < 16; ++ee)
    if (lv[ee] > mx) { mx = lv[ee]; am = ee; }   // first-argmax like np
  float sum = 0.f;
#pragma unroll
  for (int ee = 0; ee < 16; ++ee) sum += expf(lv[ee] - mx);
  if (lane == 0) { pmax[n] = 1.f / sum; route[n] = am; }
}

// one wave per expert; token-order position via ballot prefix
__global__ __launch_bounds__(64) void scan_kernel(const int *route, int *slot, int cap) {
  const int e = blockIdx.x, lane = threadIdx.x;
  int base = 0;
  for (int i = 0; i < N_TOK / 64; ++i) {
    const int n = i * 64 + lane;
    const bool m = (route[n] == e);
    const unsigned long long bal = __ballot(m);
    if (m) {
      const int pos = base + __popcll(bal & ((1ull << lane) - 1ull));
      slot[n] = (pos < cap) ? e * cap + pos : -1;
    }
    base += __popcll(bal);
  }
}

__global__ __launch_bounds__(256) void gather_kernel(const u16 *h2b, const int *slot, u16 *xe) {
  const int n = blockIdx.x;
  const int s = slot[n];
  if (s < 0) return;
  ((uint2 *)(xe + (long)s * DMODEL))[threadIdx.x] =
      ((const uint2 *)(h2b + (long)n * DMODEL))[threadIdx.x];
}

// ---------------------------------------------------------------------------
// MoE expert GEMM: C[M,Nc] = A @ W^T + bias. A bf16 [M,K], W fp32 [Nc,K]
// (converted to bf16 at B-stage). Tile 128x64; wave w: rows w*32..+31.
// Grid x splits M (2 blocks for M=160) -> 2x blocks vs 256-row tile.
// ---------------------------------------------------------------------------
struct MoeP {
  const u16 *A; long sA; int lda;
  const float *W; long sW;
  const float *bias; long sB;
  u16 *C; long sC; int ldc;
  int M, K, relu;
};

__global__ __launch_bounds__(256) void gemm_moe(MoeP p) {
  __shared__ u16 As[128 * 32];   // 8 KB
  __shared__ u16 Bs[64][40];     // bf16-converted B tile, padded (16B-aligned rows)
  const int tid = threadIdx.x, lane = tid & 63, wave = tid >> 6;
  const int z = blockIdx.z, n0 = blockIdx.y * 64, m0 = blockIdx.x * 128;
  const u16 *A = p.A + (long)z * p.sA;
  const float *W = p.W + (long)z * p.sW;
  const float *bias = p.bias + (long)z * p.sB;
  const int srow = tid >> 2, scol = (tid & 3) * 8;
  const int R0 = wave * 32;
  const int l15 = lane & 15, quad = lane >> 4;

  f32x4 acc[2][4];
#pragma unroll
  for (int i = 0; i < 2; ++i)
#pragma unroll
    for (int j = 0; j < 4; ++j) acc[i][j] = (f32x4){0.f, 0.f, 0.f, 0.f};

  for (int s = 0; s < (p.K >> 5); ++s) {
    const int kk = s << 5;
    __syncthreads();
#pragma unroll
    for (int h = 0; h < 2; ++h) {
      int ar = m0 + h * 64 + srow;
      if (ar >= p.M) ar = p.M - 1;  // M=160: clamp ragged rows
      gll16(A + (long)ar * p.lda + kk + scol, &As[(h * 64 + wave * 16) * 32]);
    }
    {  // B fp32 tile -> bf16 at stage (converted once, read by all 4 waves)
      const int br = tid >> 2, bc = (tid & 3) * 8;
      const float4 *src = (const float4 *)(W + (long)(n0 + br) * p.K + kk + bc);
      const float4 f0 = src[0], f1 = src[1];
      u16x8 bv;
      bv[0] = f2b(f0.x); bv[1] = f2b(f0.y); bv[2] = f2b(f0.z); bv[3] = f2b(f0.w);
      bv[4] = f2b(f1.x); bv[5] = f2b(f1.y); bv[6] = f2b(f1.z); bv[7] = f2b(f1.w);
      *(u16x8 *)&Bs[br][bc] = bv;
    }
    __syncthreads();
    u16x8 a[2], b[4];
#pragma unroll
    for (int i = 0; i < 2; ++i)
      a[i] = *(const u16x8 *)&As[(R0 + i * 16 + l15) * 32 + quad * 8];
#pragma unroll
    for (int j = 0; j < 4; ++j)
      b[j] = *(const u16x8 *)&Bs[j * 16 + l15][quad * 8];
#pragma unroll
    for (int i = 0; i < 2; ++i)
#pragma unroll
      for (int j = 0; j < 4; ++j) acc[i][j] = mfma16(a[i], b[j], acc[i][j]);
  }

#pragma unroll
  for (int j = 0; j < 4; ++j) {
    const int n = n0 + j * 16 + l15;
    const float bv = bias[n];
#pragma unroll
    for (int i = 0; i < 2; ++i)
#pragma unroll
      for (int r = 0; r < 4; ++r) {
        const int m = m0 + R0 + i * 16 + quad * 4 + r;
        if (m >= p.M) continue;
        float v = acc[i][j][r] + bv;
        if (p.relu) v = v > 0.f ? v : 0.f;
        p.C[(long)m * p.ldc + n + (long)z * p.sC] = f2b(v);
      }
  }
}

__global__ __launch_bounds__(256) void combine_kernel(const float *x2, const float *h2f,
                                                      const u16 *ye, const float *pmax,
                                                      const int *slot, float *out) {
  const int n = blockIdx.x, t = threadIdx.x;
  const float pm = pmax[n];
  const int s = slot[n];
  float y[4];
  if (s >= 0) {
    const uint2 u = ((const uint2 *)(ye + (long)s * DMODEL))[t];
    y[0] = b2f((u16)(u.x & 0xffff)); y[1] = b2f((u16)(u.x >> 16));
    y[2] = b2f((u16)(u.y & 0xffff)); y[3] = b2f((u16)(u.y >> 16));
  } else {
    const float4 hv = ((const float4 *)(h2f + (long)n * DMODEL))[t];
    y[0] = hv.x; y[1] = hv.y; y[2] = hv.z; y[3] = hv.w;
  }
  const float4 xv = ((const float4 *)(x2 + (long)n * DMODEL))[t];
  float4 ov;
  ov.x = xv.x + pm * y[0]; ov.y = xv.y + pm * y[1];
  ov.z = xv.z + pm * y[2]; ov.w = xv.w + pm * y[3];
  ((float4 *)(out + (long)n * DMODEL))[t] = ov;
}

// ---------------------------------------------------------------------------
extern "C" void kernel_launch(void* const* d_in, const int* in_sizes, int n_in,
                              void* d_out, int out_size, void* d_ws, size_t ws_size,
                              hipStream_t stream) {
  const float *x    = (const float *)d_in[0];
  const float *wk   = (const float *)d_in[1],  *bk  = (const float *)d_in[2];
  const float *wq   = (const float *)d_in[3],  *bq  = (const float *)d_in[4];
  const float *wv   = (const float *)d_in[5],  *bv  = (const float *)d_in[6];
  const float *ipw  = (const float *)d_in[7],  *ipb = (const float *)d_in[8];
  const float *opw  = (const float *)d_in[9],  *opb = (const float *)d_in[10];
  const float *ln1w = (const float *)d_in[11], *ln1b = (const float *)d_in[12];
  const float *ln2w = (const float *)d_in[13], *ln2b = (const float *)d_in[14];
  const float *rw   = (const float *)d_in[15], *rb  = (const float *)d_in[16];
  const float *w1   = (const float *)d_in[17], *b1  = (const float *)d_in[18];
  const float *w2   = (const float *)d_in[19], *b2  = (const float *)d_in[20];
  // d_in[21] = causal_mask: unused (mask applied analytically)

  char *ws = (char *)d_ws;
  const size_t MB = 1ull << 20;
  // lifetimes: regions reused once the prior tenant is dead (see stage order)
  u16 *WqkvH = (u16 *)(ws + 0 * MB);    // 6 MiB   (dead after stage1)
  u16 *WqkvL = (u16 *)(ws + 6 * MB);    // 6 MiB
  u16 *IpH   = (u16 *)(ws + 12 * MB);   // 6 MiB   (dead after stage2)
  u16 *IpL   = (u16 *)(ws + 18 * MB);   // 6 MiB
  u16 *OpH   = (u16 *)(ws + 24 * MB);   // 2 MiB   (dead after outproj)
  u16 *OpL   = (u16 *)(ws + 26 * MB);   // 2 MiB
  u16 *Hh    = (u16 *)(ws + 28 * MB);   // 4 MiB   (dead after stage1)
  u16 *Hl    = (u16 *)(ws + 32 * MB);   // 4 MiB
  u16 *G1h   = (u16 *)(ws + 36 * MB);   // 12 MiB  (dead after stage2)
  u16 *G1l   = (u16 *)(ws + 48 * MB);   // 12 MiB
  u16 *Qh    = (u16 *)(ws + 0 * MB);    // 12 MiB  (over Wqkv; dead after attn)
  u16 *Ql    = (u16 *)(ws + 60 * MB);   // 12 MiB  (dead after attn)
  u16 *Vtgh  = (u16 *)(ws + 36 * MB);   // 4 MiB   (over dead G1h; dead after attn)
  u16 *Vtgl  = (u16 *)(ws + 40 * MB);   // 4 MiB
  u16 *CTh   = (u16 *)(ws + 28 * MB);   // 4 MiB   (over Hh; dead after outproj)
  u16 *CTl   = (u16 *)(ws + 32 * MB);   // 4 MiB
  float *x2  = (float *)(ws + 56 * MB); // 8 MiB   (over G1l tail/Ql head; live to end)
  float *h2f = (float *)(ws + 64 * MB); // 8 MiB   (over Ql; live to end)
  u16 *h2b   = (u16 *)(ws + 72 * MB);   // 4 MiB
  float *pmax = (float *)(ws + 76 * MB);
  int *route  = (int *)(ws + 76 * MB + 32768);
  int *slot   = (int *)(ws + 76 * MB + 65536);
  u16 *xe  = (u16 *)(ws + 20 * MB);     // 5 MiB  (over IpL/OpH; dead after gemm1)
  u16 *h1e = (u16 *)(ws + 0 * MB);      // 20 MiB (over Qh/IpH/IpL; dead after gemm2)
  u16 *ye  = (u16 *)(ws + 26 * MB);     // 5 MiB  (over OpL/CTh; live to combine)

  // 0) split fp32 weights -> bf16 hi/lo
  split_kernel<<<1024, 256, 0, stream>>>(wk, WqkvH, WqkvL, 1024 * 1024 / 4);
  split_kernel<<<1024, 256, 0, stream>>>(wq, WqkvH + 1024 * 1024, WqkvL + 1024 * 1024, 1024 * 1024 / 4);
  split_kernel<<<1024, 256, 0, stream>>>(wv, WqkvH + 2 * 1024 * 1024, WqkvL + 2 * 1024 * 1024, 1024 * 1024 / 4);
  split_kernel<<<3072, 256, 0, stream>>>(ipw, IpH, IpL, 3 * 1024 * 1024 / 4);
  split_kernel<<<1024, 256, 0, stream>>>(opw, OpH, OpL, 1024 * 1024 / 4);

  // 1) LN1 -> split h
  ln1_kernel<<<N_TOK, 256, 0, stream>>>(x, ln1w, ln1b, Hh, Hl);

  // 2) stage1: q_in|k_in|v_in = h @ {wk,wq,wv}^T + {bk,bq,bv} -> G1 [2048,3072]
  {
    GemmSP p{};
    p.Ah = Hh; p.Al = Hl; p.sA = 0; p.lda = 1024;
    p.Wh = WqkvH; p.Wl = WqkvL; p.sWp = 1024 * 1024;
    p.sB = -1; p.B0 = bk; p.B1 = bq; p.B2 = bv;
    p.Ch = G1h; p.Cl = G1l; p.sC = 1024; p.ldc = 3072; p.K = 1024;
    gemm_split<<<dim3(16, 8, 3), 256, 0, stream>>>(p);
  }
  // 3) stage2: q|k|v = {q_in,k_in,v_in} @ ipw-chunk^T + ipb -> QKV [2048,3072]
  {
    GemmSP p{};
    p.Ah = G1h; p.Al = G1l; p.sA = 1024; p.lda = 3072;
    p.Wh = IpH; p.Wl = IpL; p.sWp = 1024 * 1024;
    p.bias = ipb; p.sB = 1024;
    p.Ch = Qh; p.Cl = Ql; p.sC = 1024; p.ldc = 3072; p.K = 1024;
    gemm_split<<<dim3(16, 8, 3), 256, 0, stream>>>(p);
  }
  // 3b) transpose V columns -> Vtg [1024][2048] (hi/lo)
  vtrans_kernel<<<dim3(32, 16), 256, 0, stream>>>(Qh, Ql, Vtgh, Vtgl);

  // 4) flash attention -> ctx split [2048,1024]
  attn_kernel<<<dim3(512), 256, 0, stream>>>(Qh, Ql, Vtgh, Vtgl, CTh, CTl);

  // 5) out-proj + residual: x2 = x + ctx @ opw^T + opb  (fp32)
  {
    GemmSP p{};
    p.Ah = CTh; p.Al = CTl; p.sA = 0; p.lda = 1024;
    p.Wh = OpH; p.Wl = OpL; p.sWp = 0;
    p.bias = opb; p.sB = 0;
    p.Rres = x;
    p.Cf = x2; p.sC = 0; p.ldc = 1024; p.K = 1024;
    gemm_split<<<dim3(16, 8, 1), 256, 0, stream>>>(p);
  }
  // 6) LN2 -> h2 (fp32 + bf16)
  ln2_kernel<<<N_TOK, 256, 0, stream>>>(x2, ln2w, ln2b, h2f, h2b);
  // 7) router softmax top-1 (pure fp32)
  router_kernel<<<N_TOK, 64, 0, stream>>>(h2f, rw, rb, pmax, route);
  // 8) capacity scan -> slot
  scan_kernel<<<NEXP, 64, 0, stream>>>(route, slot, CAP);
  // 9) gather kept tokens -> xe [E*cap, D] bf16
  gather_kernel<<<N_TOK, 256, 0, stream>>>(h2b, slot, xe);
  // 10) expert GEMM1: h1e = relu(xe @ w1[e]^T + b1[e])   [160,4096]/expert
  {
    MoeP p{};
    p.A = xe; p.sA = (long)CAP * 1024; p.lda = 1024;
    p.W = w1; p.sW = (long)FEXP * 1024;
    p.bias = b1; p.sB = FEXP;
    p.C = h1e; p.sC = (long)CAP * FEXP; p.ldc = FEXP;
    p.M = CAP; p.K = 1024; p.relu = 1;
    gemm_moe<<<dim3(2, 64, NEXP), 256, 0, stream>>>(p);
  }
  // 11) expert GEMM2: ye = h1e @ w2[e]^T + b2[e]   [160,1024]/expert
  {
    MoeP p{};
    p.A = h1e; p.sA = (long)CAP * FEXP; p.lda = FEXP;
    p.W = w2; p.sW = (long)1024 * FEXP;
    p.bias = b2; p.sB = 1024;
    p.C = ye; p.sC = (long)CAP * 1024; p.ldc = 1024;
    p.M = CAP; p.K = FEXP; p.relu = 0;
    gemm_moe<<<dim3(2, 16, NEXP), 256, 0, stream>>>(p);
  }
  // 12) out = x2 + pmax * (kept ? ye[slot] : h2)   (fp32)
  combine_kernel<<<N_TOK, 256, 0, stream>>>(x2, h2f, ye, pmax, slot, (float *)d_out);
}